// Round 1
// baseline (221.968 us; speedup 1.0000x reference)
//
#include <hip/hip_runtime.h>
#include <math.h>

#define T_LEN 4096
#define CHUNK 16
#define NTHR  256
#define ESTRIDE 15   // 9 (A) + 3 (b) + 3 (c); odd stride -> conflict-free LDS

__device__ __forceinline__ void make_A(float wx, float wy, float wz, float* A) {
    const float dt = 1.0f / 200.0f;
    float n = sqrtf(wx*wx + wy*wy + wz*wz);
    float theta = n * dt;
    float inv = 1.0f / (n + 1e-8f);
    float x = wx * inv, y = wy * inv, z = wz * inv;
    float s = sinf(theta);
    float c = cosf(theta);
    float oc = 1.0f - c;
    A[0] = 1.0f + oc * (-(y*y + z*z));
    A[1] = -s*z + oc * (x*y);
    A[2] =  s*y + oc * (x*z);
    A[3] =  s*z + oc * (x*y);
    A[4] = 1.0f + oc * (-(x*x + z*z));
    A[5] = -s*x + oc * (y*z);
    A[6] = -s*y + oc * (x*z);
    A[7] =  s*x + oc * (y*z);
    A[8] = 1.0f + oc * (-(x*x + y*y));
}

__device__ __forceinline__ void matmul3(const float* R, const float* A, float* N) {
#pragma unroll
    for (int i = 0; i < 3; ++i) {
        N[i*3+0] = R[i*3+0]*A[0] + R[i*3+1]*A[3] + R[i*3+2]*A[6];
        N[i*3+1] = R[i*3+0]*A[1] + R[i*3+1]*A[4] + R[i*3+2]*A[7];
        N[i*3+2] = R[i*3+0]*A[2] + R[i*3+1]*A[5] + R[i*3+2]*A[8];
    }
}

// One reference step applied to state (R, v, p). Identical numerics to the
// reference replay; also used to build chunk elements (start from identity).
__device__ __forceinline__ void step(float* R, float* v, float* p,
                                     float wx, float wy, float wz,
                                     float ax, float ay, float az) {
    const float dt   = 1.0f / 200.0f;
    const float dt2h = dt * dt * 0.5f;
    float A[9], N[9];
    make_A(wx, wy, wz, A);
    matmul3(R, A, N);
#pragma unroll
    for (int i = 0; i < 9; ++i) R[i] = N[i];
    float rax = R[0]*ax + R[1]*ay + R[2]*az;
    float ray = R[3]*ax + R[4]*ay + R[5]*az;
    float raz = R[6]*ax + R[7]*ay + R[8]*az;
    v[0] += rax*dt; v[1] += ray*dt; v[2] += raz*dt;
    p[0] += v[0]*dt + rax*dt2h;
    p[1] += v[1]*dt + ray*dt2h;
    p[2] += v[2]*dt + raz*dt2h;
}

__global__ __launch_bounds__(NTHR)
void preint_kernel(const float* __restrict__ in, float* __restrict__ out) {
    const int b = blockIdx.x;
    const int t = threadIdx.x;
    const float dt = 1.0f / 200.0f;

    const float* bin  = in  + (size_t)b * T_LEN * 6;
    float*       bout = out + (size_t)b * T_LEN * 16;
    const float2* cin2 = (const float2*)(bin + (size_t)t * CHUNK * 6);

    // ---- Phase 1: per-thread chunk element (state from identity) ----
    float R[9] = {1,0,0, 0,1,0, 0,0,1};
    float v[3] = {0,0,0};
    float p[3] = {0,0,0};
#pragma unroll 4
    for (int k = 0; k < CHUNK; ++k) {
        float2 u0 = cin2[k*3+0];
        float2 u1 = cin2[k*3+1];
        float2 u2 = cin2[k*3+2];
        step(R, v, p, u0.x, u0.y, u1.x, u1.y, u2.x, u2.y);
    }

    __shared__ float lds[NTHR * ESTRIDE];
    float* e = lds + t * ESTRIDE;
#pragma unroll
    for (int i = 0; i < 9; ++i) e[i] = R[i];
    e[9]  = v[0]; e[10] = v[1]; e[11] = v[2];
    e[12] = p[0]; e[13] = p[1]; e[14] = p[2];
    __syncthreads();

    // ---- Phase 2: Hillis-Steele inclusive scan over 256 elements ----
    // Right operand (mine) covers exactly d chunks in round d (for t >= d),
    // so tau2 = d*CHUNK*dt is uniform per round.
    for (int d = 1; d < NTHR; d <<= 1) {
        float L[15];
        const bool act = (t >= d);
        if (act) {
            const float* src = lds + (t - d) * ESTRIDE;
#pragma unroll
            for (int i = 0; i < 15; ++i) L[i] = src[i];
        }
        __syncthreads();
        if (act) {
            const float tau2 = (float)(d * CHUNK) * dt;
            float NA[9];
            matmul3(L, R, NA);                       // A = L.A @ my.A
            float nb0 = L[9]  + L[0]*v[0] + L[1]*v[1] + L[2]*v[2];
            float nb1 = L[10] + L[3]*v[0] + L[4]*v[1] + L[5]*v[2];
            float nb2 = L[11] + L[6]*v[0] + L[7]*v[1] + L[8]*v[2];
            float nc0 = L[12] + tau2*L[9]  + L[0]*p[0] + L[1]*p[1] + L[2]*p[2];
            float nc1 = L[13] + tau2*L[10] + L[3]*p[0] + L[4]*p[1] + L[5]*p[2];
            float nc2 = L[14] + tau2*L[11] + L[6]*p[0] + L[7]*p[1] + L[8]*p[2];
#pragma unroll
            for (int i = 0; i < 9; ++i) R[i] = NA[i];
            v[0] = nb0; v[1] = nb1; v[2] = nb2;
            p[0] = nc0; p[1] = nc1; p[2] = nc2;
#pragma unroll
            for (int i = 0; i < 9; ++i) e[i] = R[i];
            e[9]  = v[0]; e[10] = v[1]; e[11] = v[2];
            e[12] = p[0]; e[13] = p[1]; e[14] = p[2];
        }
        __syncthreads();
    }

    // ---- Phase 3: replay chunk from exclusive-prefix state, emit outputs ----
    float S[9]  = {1,0,0, 0,1,0, 0,0,1};
    float sv[3] = {0,0,0};
    float sp[3] = {0,0,0};
    if (t > 0) {
        const float* src = lds + (t - 1) * ESTRIDE;
#pragma unroll
        for (int i = 0; i < 9; ++i) S[i] = src[i];
        sv[0] = src[9];  sv[1] = src[10]; sv[2] = src[11];
        sp[0] = src[12]; sp[1] = src[13]; sp[2] = src[14];
    }

#pragma unroll 4
    for (int k = 0; k < CHUNK; ++k) {
        float2 u0 = cin2[k*3+0];
        float2 u1 = cin2[k*3+1];
        float2 u2 = cin2[k*3+2];
        step(S, sv, sp, u0.x, u0.y, u1.x, u1.y, u2.x, u2.y);

        // quaternion via reference's axis-angle path
        float tr  = S[0] + S[4] + S[8];
        float ca  = fminf(fmaxf(0.5f * (tr - 1.0f), -1.0f + 1e-7f), 1.0f - 1e-7f);
        float ang = acosf(ca);
        float isc = 1.0f / (2.0f * sinf(ang) + 1e-8f);
        float axx = (S[7] - S[5]) * isc;   // R21 - R12
        float axy = (S[2] - S[6]) * isc;   // R02 - R20
        float axz = (S[3] - S[1]) * isc;   // R10 - R01
        float h   = 0.5f * ang;
        float qw  = cosf(h);
        float qs  = sinf(h);

        float4* orow = (float4*)(bout + (size_t)(t * CHUNK + k) * 16);
        orow[0] = make_float4(u0.x, u0.y, u1.x, u1.y);
        orow[1] = make_float4(u2.x, u2.y, sp[0], sp[1]);
        orow[2] = make_float4(sp[2], qw, axx * qs, axy * qs);
        orow[3] = make_float4(axz * qs, sv[0], sv[1], sv[2]);
    }
}

extern "C" void kernel_launch(void* const* d_in, const int* in_sizes, int n_in,
                              void* d_out, int out_size, void* d_ws, size_t ws_size,
                              hipStream_t stream) {
    const float* in = (const float*)d_in[0];
    float* out = (float*)d_out;
    const int B = in_sizes[0] / (T_LEN * 6);   // 512
    preint_kernel<<<dim3(B), dim3(NTHR), 0, stream>>>(in, out);
}

// Round 2
// 207.345 us; speedup vs baseline: 1.0705x; 1.0705x over previous
//
#include <hip/hip_runtime.h>
#include <math.h>

#define T_LEN 4096
#define CHUNK 8
#define NTHR  512
#define ESTRIDE 15   // 9 (A) + 3 (b) + 3 (c); odd stride -> conflict-free LDS

__device__ __forceinline__ void make_A(float wx, float wy, float wz, float* A) {
    const float dt = 1.0f / 200.0f;
    float n = sqrtf(wx*wx + wy*wy + wz*wz);
    float theta = n * dt;
    float inv = 1.0f / (n + 1e-8f);
    float x = wx * inv, y = wy * inv, z = wz * inv;
    float s = sinf(theta);
    float c = cosf(theta);
    float oc = 1.0f - c;
    A[0] = 1.0f + oc * (-(y*y + z*z));
    A[1] = -s*z + oc * (x*y);
    A[2] =  s*y + oc * (x*z);
    A[3] =  s*z + oc * (x*y);
    A[4] = 1.0f + oc * (-(x*x + z*z));
    A[5] = -s*x + oc * (y*z);
    A[6] = -s*y + oc * (x*z);
    A[7] =  s*x + oc * (y*z);
    A[8] = 1.0f + oc * (-(x*x + y*y));
}

__device__ __forceinline__ void matmul3(const float* R, const float* A, float* N) {
#pragma unroll
    for (int i = 0; i < 3; ++i) {
        N[i*3+0] = R[i*3+0]*A[0] + R[i*3+1]*A[3] + R[i*3+2]*A[6];
        N[i*3+1] = R[i*3+0]*A[1] + R[i*3+1]*A[4] + R[i*3+2]*A[7];
        N[i*3+2] = R[i*3+0]*A[2] + R[i*3+1]*A[5] + R[i*3+2]*A[8];
    }
}

// One reference step applied to state (R, v, p). Identical numerics to the
// reference replay; also used to build chunk elements (start from identity).
__device__ __forceinline__ void step(float* R, float* v, float* p,
                                     float wx, float wy, float wz,
                                     float ax, float ay, float az) {
    const float dt   = 1.0f / 200.0f;
    const float dt2h = dt * dt * 0.5f;
    float A[9], N[9];
    make_A(wx, wy, wz, A);
    matmul3(R, A, N);
#pragma unroll
    for (int i = 0; i < 9; ++i) R[i] = N[i];
    float rax = R[0]*ax + R[1]*ay + R[2]*az;
    float ray = R[3]*ax + R[4]*ay + R[5]*az;
    float raz = R[6]*ax + R[7]*ay + R[8]*az;
    v[0] += rax*dt; v[1] += ray*dt; v[2] += raz*dt;
    p[0] += v[0]*dt + rax*dt2h;
    p[1] += v[1]*dt + ray*dt2h;
    p[2] += v[2]*dt + raz*dt2h;
}

__global__ __launch_bounds__(NTHR)
void preint_kernel(const float* __restrict__ in, float* __restrict__ out) {
    const int b = blockIdx.x;
    const int t = threadIdx.x;
    const float dt = 1.0f / 200.0f;

    const float* bin  = in  + (size_t)b * T_LEN * 6;
    float*       bout = out + (size_t)b * T_LEN * 16;

    // ---- Load this thread's chunk input into registers (kept across scan) ----
    float in_reg[CHUNK * 6];
    {
        const float4* src4 = (const float4*)(bin + (size_t)t * CHUNK * 6);
#pragma unroll
        for (int i = 0; i < (CHUNK * 6) / 4; ++i) {
            float4 u = src4[i];
            in_reg[i*4+0] = u.x; in_reg[i*4+1] = u.y;
            in_reg[i*4+2] = u.z; in_reg[i*4+3] = u.w;
        }
    }

    // ---- Phase 1: per-thread chunk element (state from identity) ----
    float R[9] = {1,0,0, 0,1,0, 0,0,1};
    float v[3] = {0,0,0};
    float p[3] = {0,0,0};
#pragma unroll
    for (int k = 0; k < CHUNK; ++k) {
        const float* u = in_reg + k * 6;
        step(R, v, p, u[0], u[1], u[2], u[3], u[4], u[5]);
    }

    __shared__ float lds[NTHR * ESTRIDE];
    float* e = lds + t * ESTRIDE;
#pragma unroll
    for (int i = 0; i < 9; ++i) e[i] = R[i];
    e[9]  = v[0]; e[10] = v[1]; e[11] = v[2];
    e[12] = p[0]; e[13] = p[1]; e[14] = p[2];
    __syncthreads();

    // ---- Phase 2: Hillis-Steele inclusive scan over NTHR elements ----
    // Left operand covers exactly d chunks in round d, so tau2 = d*CHUNK*dt.
    for (int d = 1; d < NTHR; d <<= 1) {
        float L[15];
        const bool act = (t >= d);
        if (act) {
            const float* src = lds + (t - d) * ESTRIDE;
#pragma unroll
            for (int i = 0; i < 15; ++i) L[i] = src[i];
        }
        __syncthreads();
        if (act) {
            const float tau2 = (float)(d * CHUNK) * dt;
            float NA[9];
            matmul3(L, R, NA);                       // A = L.A @ my.A
            float nb0 = L[9]  + L[0]*v[0] + L[1]*v[1] + L[2]*v[2];
            float nb1 = L[10] + L[3]*v[0] + L[4]*v[1] + L[5]*v[2];
            float nb2 = L[11] + L[6]*v[0] + L[7]*v[1] + L[8]*v[2];
            float nc0 = L[12] + tau2*L[9]  + L[0]*p[0] + L[1]*p[1] + L[2]*p[2];
            float nc1 = L[13] + tau2*L[10] + L[3]*p[0] + L[4]*p[1] + L[5]*p[2];
            float nc2 = L[14] + tau2*L[11] + L[6]*p[0] + L[7]*p[1] + L[8]*p[2];
#pragma unroll
            for (int i = 0; i < 9; ++i) R[i] = NA[i];
            v[0] = nb0; v[1] = nb1; v[2] = nb2;
            p[0] = nc0; p[1] = nc1; p[2] = nc2;
#pragma unroll
            for (int i = 0; i < 9; ++i) e[i] = R[i];
            e[9]  = v[0]; e[10] = v[1]; e[11] = v[2];
            e[12] = p[0]; e[13] = p[1]; e[14] = p[2];
        }
        __syncthreads();
    }

    // ---- Phase 3: replay chunk from exclusive-prefix state, emit outputs ----
    float S[9]  = {1,0,0, 0,1,0, 0,0,1};
    float sv[3] = {0,0,0};
    float sp[3] = {0,0,0};
    if (t > 0) {
        const float* src = lds + (t - 1) * ESTRIDE;
#pragma unroll
        for (int i = 0; i < 9; ++i) S[i] = src[i];
        sv[0] = src[9];  sv[1] = src[10]; sv[2] = src[11];
        sp[0] = src[12]; sp[1] = src[13]; sp[2] = src[14];
    }

    // Emit rows in pairs so each lane writes a full, aligned 128B L2 line.
#pragma unroll
    for (int kk = 0; kk < CHUNK; kk += 2) {
        float4 row[8];
#pragma unroll
        for (int j = 0; j < 2; ++j) {
            const int k = kk + j;
            const float* u = in_reg + k * 6;
            step(S, sv, sp, u[0], u[1], u[2], u[3], u[4], u[5]);

            // quaternion, closed-form (== reference's acos/sin path with its clip):
            //   ca = clip((tr-1)/2); qw = cos(ang/2) = sqrt((1+ca)/2)
            //   qvec = d * sin(h)/(2 sin(ang)) = d / (4 qw),  d = (R21-R12, R02-R20, R10-R01)
            float tr  = S[0] + S[4] + S[8];
            float ca  = fminf(fmaxf(0.5f * (tr - 1.0f), -1.0f + 1e-7f), 1.0f - 1e-7f);
            float qw  = sqrtf(0.5f * (1.0f + ca));
            float i4  = 0.25f / qw;
            float qx  = (S[7] - S[5]) * i4;
            float qy  = (S[2] - S[6]) * i4;
            float qz  = (S[3] - S[1]) * i4;

            row[j*4+0] = make_float4(u[0], u[1], u[2], u[3]);
            row[j*4+1] = make_float4(u[4], u[5], sp[0], sp[1]);
            row[j*4+2] = make_float4(sp[2], qw, qx, qy);
            row[j*4+3] = make_float4(qz, sv[0], sv[1], sv[2]);
        }
        float4* orow = (float4*)(bout + (size_t)(t * CHUNK + kk) * 16);
#pragma unroll
        for (int i = 0; i < 8; ++i) orow[i] = row[i];
    }
}

extern "C" void kernel_launch(void* const* d_in, const int* in_sizes, int n_in,
                              void* d_out, int out_size, void* d_ws, size_t ws_size,
                              hipStream_t stream) {
    const float* in = (const float*)d_in[0];
    float* out = (float*)d_out;
    const int B = in_sizes[0] / (T_LEN * 6);   // 512
    preint_kernel<<<dim3(B), dim3(NTHR), 0, stream>>>(in, out);
}